// Round 4
// baseline (1145.125 us; speedup 1.0000x reference)
//
#include <hip/hip_runtime.h>

typedef __attribute__((ext_vector_type(8))) short short8;
typedef __attribute__((ext_vector_type(4))) float floatx4;

__device__ __forceinline__ unsigned short f2bf(float f) {
  union { float f; unsigned int u; } un; un.f = f;
  unsigned int r = un.u + 0x7FFFu + ((un.u >> 16) & 1u);
  return (unsigned short)(r >> 16);
}
__device__ __forceinline__ float bf2f(unsigned short h) {
  union { unsigned int u; float f; } un; un.u = ((unsigned int)h) << 16;
  return un.f;
}

__device__ __forceinline__ void async_ld16(const unsigned short* g, unsigned short* l) {
  __builtin_amdgcn_global_load_lds(
      (const __attribute__((address_space(1))) void*)g,
      (__attribute__((address_space(3))) void*)l, 16, 0, 0);
}

// ---------------------------------------------------------------------------
// Persistent vocab GEMM: C[M,32000] = A[M,512](bf16) @ W[32000,512](bf16)^T + b.
// Round-3 result: bytes are minimal (FETCH 26 MB, WRITE 320 MB) but the
// kernel sat at 1972 cyc/step vs a ~700 cyc/step LDS/MFMA floor -> the
// per-step __syncthreads drained vmcnt(0) for an A-load issued only one
// phase earlier (L3-latency miss: C-writes evict A from L2). Round-4 fix:
//   - 3 A-buffers (8 KB each), counted vmcnt, ONE raw s_barrier per step.
//     stage_a(s+2) is issued after barrier(s): every wave's MFMAs precede
//     its barrier, so buf[(s-1)%3] is fully consumed -> overwrite safe.
//     A-load gets 2 full compute phases (~1400 cyc) to land; steady-state
//     wait = vmcnt(1), never 0.
//   - epilogue stores (every 8th step) enter the vmcnt FIFO: the two steps
//     after an epilogue wait vmcnt(17) (16 stores + 1 newer stage in
//     flight), so the write queue is never synchronously drained.
// LDS = 128 KB (B slab, XOR-swz) + 3x8 KB (A) = 152 KB -> 1 block/CU,
// 512 thr (8 waves 2Mx4N). Grid = 250 = N/128, single generation.
// ---------------------------------------------------------------------------
__global__ __launch_bounds__(512, 1)
void gemm_vocab(const unsigned short* __restrict__ A, const unsigned short* __restrict__ B,
                const float* __restrict__ bias, float* __restrict__ C, int M, int N) {
  __shared__ __align__(16) unsigned short sB[65536];    // [128][512] elems, XOR-swz
  __shared__ __align__(16) unsigned short sA[3][4096];  // [64][64] per buf, XOR-swz
  const int tid = threadIdx.x;
  const int lane = tid & 63;
  const int wave = tid >> 6;
  const int n0 = blockIdx.x * 128;
  const int fr = lane & 15;
  const int q = lane >> 4;
  const int wm = (wave >> 2) * 32;  // 2 wave-rows over 64
  const int wn = (wave & 3) * 32;   // 4 wave-cols over 128

  // ---- prologue: stage full B n-slab (16 loads/thread, oldest in FIFO).
  for (int ro = 0; ro < 16; ro++) {
    int rr = ro * 8 + wave;
    async_ld16(B + (size_t)(n0 + rr) * 512 + ((lane ^ (rr & 7)) << 3),
               &sB[ro * 4096 + wave * 512]);
  }

  // A stage for flat step s (mt = s>>3, kt = s&7): 64x64 tile, 1 ld/thread.
  auto stage_a = [&](int s, int buf) {
    int mt = s >> 3, kt = s & 7;
    int r = tid >> 3, cb = tid & 7;
    async_ld16(A + (size_t)(mt * 64 + r) * 512 + (kt << 6) + ((cb ^ (r & 7)) << 3),
               &sA[buf][wave * 512]);
  };

  floatx4 acc[2][2];
#pragma unroll
  for (int i = 0; i < 2; i++)
#pragma unroll
    for (int j = 0; j < 2; j++) acc[i][j] = (floatx4){0.f, 0.f, 0.f, 0.f};

  stage_a(0, 0);
  stage_a(1, 1);
  const int nsteps = (M >> 6) << 3;
  int bufc = 0;  // = s % 3
  for (int s = 0; s < nsteps; s++) {
    // Counted wait: stage(s) landed; stage(s+1) [and post-epilogue stores]
    // stay in flight. vmcnt FIFO after an epilogue (stores issued at end of
    // step 8m-1, after stage(8m+1)): steps 8m+0/8m+1 need vmcnt(17).
    if (s + 1 >= nsteps)            asm volatile("s_waitcnt vmcnt(0)" ::: "memory");
    else if (s >= 8 && (s & 7) < 2) asm volatile("s_waitcnt vmcnt(17)" ::: "memory");
    else                            asm volatile("s_waitcnt vmcnt(1)" ::: "memory");
    __builtin_amdgcn_s_barrier();   // buf[s%3] staged for every wave

    if (s + 2 < nsteps) {
      int b2 = bufc + 2; if (b2 >= 3) b2 -= 3;
      stage_a(s + 2, b2);           // overwrites buf consumed at step s-1
    }

    const unsigned short* pA = sA[bufc];
    const int kt = s & 7;
#pragma unroll
    for (int kk = 0; kk < 64; kk += 32) {
      const int cba = (kk >> 3) + q;
      short8 af[2], bfr[2];
#pragma unroll
      for (int t = 0; t < 2; t++) {
        int ra = wm + t * 16 + fr;
        af[t] = *(const short8*)&pA[ra * 64 + ((cba ^ (ra & 7)) << 3)];
        int rb = wn + t * 16 + fr;
        int cbi = (kt << 3) + cba;
        bfr[t] = *(const short8*)&sB[rb * 512 + ((cbi ^ (rb & 7)) << 3)];
      }
#pragma unroll
      for (int i = 0; i < 2; i++)
#pragma unroll
        for (int j = 0; j < 2; j++)
          acc[i][j] = __builtin_amdgcn_mfma_f32_16x16x32_bf16(af[i], bfr[j], acc[i][j], 0, 0, 0);
    }
    if (kt == 7) {
      const int mt = s >> 3;
#pragma unroll
      for (int i = 0; i < 2; i++)
#pragma unroll
        for (int j = 0; j < 2; j++) {
#pragma unroll
          for (int rg = 0; rg < 4; rg++) {
            int row = mt * 64 + wm + i * 16 + q * 4 + rg;
            int col = n0 + wn + j * 16 + fr;
            C[(size_t)row * N + col] = acc[i][j][rg] + bias[col];
          }
          acc[i][j] = (floatx4){0.f, 0.f, 0.f, 0.f};
        }
    }
    bufc = (bufc == 2) ? 0 : bufc + 1;
  }
}

// ---------------------------------------------------------------------------
// GEMM: C[M,N] = A[M,K](bf16 rm) @ W[N,K](bf16 rm)^T + bias (+res fp32, relu).
// TM in {128,64}, TN=64. BK=64, 256 thr (4 waves 2x2), mfma 16x16x32.
// Triple-buffered LDS, counted vmcnt, raw barriers (see round-2 notes).
// T1: bijective XCD-chunked block remap.
// ---------------------------------------------------------------------------
template<int TM, int TN, int OUT_BF16, int RELU>
__global__ __launch_bounds__(256, (TM == 64) ? 3 : 2)
void gemm_bt(const unsigned short* __restrict__ A, const unsigned short* __restrict__ B,
             const float* __restrict__ bias, const float* __restrict__ res,
             void* __restrict__ Cout, int M, int N, int K) {
  constexpr int AELEM = TM * 64;
  constexpr int BELEM = TN * 64;
  constexpr int AIT = AELEM / 2048;
  constexpr int BIT = BELEM / 2048;
  constexpr int LPS = AIT + BIT;   // global_load_lds per thread per stage
  constexpr int FM = TM / 32;
  constexpr int FN = TN / 32;
  __shared__ __align__(16) unsigned short sA[3][AELEM];
  __shared__ __align__(16) unsigned short sB[3][BELEM];
  const int tid = threadIdx.x;
  const int lane = tid & 63;
  const int wave = tid >> 6;

  // T1: bijective XCD-chunked remap (hardware round-robins linear id % 8).
  const int gx = gridDim.x;
  const int nwg = gx * gridDim.y;
  const int ord = blockIdx.y * gx + blockIdx.x;
  const int qq = nwg >> 3, rr = nwg & 7;
  const int xcd = ord & 7, idx = ord >> 3;
  const int lin = (xcd < rr) ? (xcd * (qq + 1) + idx)
                             : (rr * (qq + 1) + (xcd - rr) * qq + idx);
  const int m0 = (lin % gx) * TM;   // M fast within an XCD chunk -> B-slab reuse
  const int n0 = (lin / gx) * TN;

  int a_off[AIT], b_off[BIT], lb[AIT > BIT ? AIT : BIT];
#pragma unroll
  for (int it = 0; it < AIT; it++) {
    int e = it * 2048 + tid * 8;
    int r = e >> 6, cb = (e >> 3) & 7;
    a_off[it] = (m0 + r) * K + ((cb ^ (r & 7)) * 8);
    lb[it] = it * 2048 + wave * 512;
  }
#pragma unroll
  for (int it = 0; it < BIT; it++) {
    int e = it * 2048 + tid * 8;
    int r = e >> 6, cb = (e >> 3) & 7;
    b_off[it] = (n0 + r) * K + ((cb ^ (r & 7)) * 8);
  }

  floatx4 acc[FM][FN];
#pragma unroll
  for (int i = 0; i < FM; i++)
#pragma unroll
    for (int j = 0; j < FN; j++) acc[i][j] = (floatx4){0.f, 0.f, 0.f, 0.f};

  const int nkt = K >> 6;
  const int wm = (wave >> 1) * (TM / 2);
  const int wn = (wave & 1) * (TN / 2);
  const int fr = lane & 15;
  const int q = lane >> 4;

  auto stage = [&](int kt, int buf) {
    const int k0 = kt << 6;
#pragma unroll
    for (int it = 0; it < AIT; it++) async_ld16(A + (size_t)a_off[it] + k0, &sA[buf][lb[it]]);
#pragma unroll
    for (int it = 0; it < BIT; it++) async_ld16(B + (size_t)b_off[it] + k0, &sB[buf][lb[it]]);
  };

  stage(0, 0);
  if (nkt > 1) stage(1, 1);
  if (nkt > 2) stage(2, 2);

  int buf = 0;
  for (int kt = 0; kt < nkt; kt++) {
    const int rem = nkt - 1 - kt;  // stages still in flight beyond kt after our wait
    if (rem >= 2)      asm volatile("s_waitcnt vmcnt(%0)" :: "n"(2 * LPS) : "memory");
    else if (rem == 1) asm volatile("s_waitcnt vmcnt(%0)" :: "n"(LPS) : "memory");
    else               asm volatile("s_waitcnt vmcnt(0)" ::: "memory");
    __builtin_amdgcn_s_barrier();   // buf[kt%3] fully staged for every wave

    const unsigned short* pA = sA[buf];
    const unsigned short* pB = sB[buf];
#pragma unroll
    for (int kk = 0; kk < 64; kk += 32) {
      short8 af[FM], bfr[FN];
      const int cba = (kk >> 3) + q;
#pragma unroll
      for (int t = 0; t < FM; t++) {
        int ra = wm + t * 16 + fr;
        af[t] = *(const short8*)&pA[ra * 64 + ((cba ^ (ra & 7)) * 8)];
      }
#pragma unroll
      for (int t = 0; t < FN; t++) {
        int rb = wn + t * 16 + fr;
        bfr[t] = *(const short8*)&pB[rb * 64 + ((cba ^ (rb & 7)) * 8)];
      }
#pragma unroll
      for (int i = 0; i < FM; i++)
#pragma unroll
        for (int j = 0; j < FN; j++)
          acc[i][j] = __builtin_amdgcn_mfma_f32_16x16x32_bf16(af[i], bfr[j], acc[i][j], 0, 0, 0);
    }

    asm volatile("s_waitcnt lgkmcnt(0)" ::: "memory");  // my reads of buf done
    __builtin_amdgcn_s_barrier();                        // everyone's reads done
    if (kt + 3 < nkt) stage(kt + 3, buf);                // overwrite is now safe
    buf = (buf == 2) ? 0 : buf + 1;
  }

#pragma unroll
  for (int i = 0; i < FM; i++) {
#pragma unroll
    for (int j = 0; j < FN; j++) {
#pragma unroll
      for (int rg = 0; rg < 4; rg++) {
        int row = m0 + wm + i * 16 + q * 4 + rg;
        int col = n0 + wn + j * 16 + fr;
        float v = acc[i][j][rg];
        if (bias) v += bias[col];
        if (res)  v += res[(size_t)row * N + col];
        if (RELU) v = v > 0.f ? v : 0.f;
        if (OUT_BF16) ((unsigned short*)Cout)[(size_t)row * N + col] = f2bf(v);
        else          ((float*)Cout)[(size_t)row * N + col] = v;
      }
    }
  }
}

// ---------------------------------------------------------------------------
// Embedding gather: x[p,e] = W_in[e, caps[p]] + b_in[e] + pos_emb[p%80, e]
// ---------------------------------------------------------------------------
__global__ __launch_bounds__(512)
void embed_kernel(const int* __restrict__ caps, const float* __restrict__ W_in,
                  const float* __restrict__ b_in, const float* __restrict__ pos,
                  float* __restrict__ x, unsigned short* __restrict__ xbf) {
  int pidx = blockIdx.x;
  int l = pidx % 80;
  int tok = caps[pidx];
  int e = threadIdx.x;
  float v = W_in[(size_t)e * 32000 + tok] + b_in[e] + pos[l * 512 + e];
  x[(size_t)pidx * 512 + e] = v;
  xbf[(size_t)pidx * 512 + e] = f2bf(v);
}

// ---------------------------------------------------------------------------
// Single LayerNorm (for LN3). One wave per row (E=512, 8 vals/lane).
// ---------------------------------------------------------------------------
__global__ __launch_bounds__(256)
void ln_kernel(const float* __restrict__ in, const float* __restrict__ w,
               const float* __restrict__ b, float* __restrict__ xout,
               unsigned short* __restrict__ xbf) {
  int row = blockIdx.x * 4 + (threadIdx.x >> 6);
  int lane = threadIdx.x & 63;
  const float* p = in + (size_t)row * 512;
  float vals[8];
  float s = 0.f, s2 = 0.f;
#pragma unroll
  for (int j = 0; j < 8; j++) {
    float t = p[lane + j * 64];
    vals[j] = t; s += t; s2 += t * t;
  }
#pragma unroll
  for (int off = 32; off; off >>= 1) { s += __shfl_xor(s, off); s2 += __shfl_xor(s2, off); }
  float mean = s * (1.f / 512.f);
  float inv = rsqrtf(s2 * (1.f / 512.f) - mean * mean + 1e-5f);
#pragma unroll
  for (int j = 0; j < 8; j++) {
    int c = lane + j * 64;
    float y = (vals[j] - mean) * inv * w[c] + b[c];
    xout[(size_t)row * 512 + c] = y;
    xbf[(size_t)row * 512 + c] = f2bf(y);
  }
}

// ---------------------------------------------------------------------------
// Fused LN1 -> +cav -> LN2 (saves a kernel + a full x round-trip per layer).
// ---------------------------------------------------------------------------
__global__ __launch_bounds__(256)
void ln2x_kernel(const float* __restrict__ in, const float* __restrict__ cav,
                 const float* __restrict__ w1, const float* __restrict__ b1,
                 const float* __restrict__ w2, const float* __restrict__ b2,
                 float* __restrict__ xout, unsigned short* __restrict__ xbf) {
  int row = blockIdx.x * 4 + (threadIdx.x >> 6);
  int lane = threadIdx.x & 63;
  const float* p = in + (size_t)row * 512;
  float vals[8];
  float s = 0.f, s2 = 0.f;
#pragma unroll
  for (int j = 0; j < 8; j++) {
    float t = p[lane + j * 64];
    vals[j] = t; s += t; s2 += t * t;
  }
#pragma unroll
  for (int off = 32; off; off >>= 1) { s += __shfl_xor(s, off); s2 += __shfl_xor(s2, off); }
  float mean = s * (1.f / 512.f);
  float inv = rsqrtf(s2 * (1.f / 512.f) - mean * mean + 1e-5f);
  float s_b = 0.f, s2_b = 0.f;
#pragma unroll
  for (int j = 0; j < 8; j++) {
    int c = lane + j * 64;
    float y = (vals[j] - mean) * inv * w1[c] + b1[c] + cav[c];
    vals[j] = y; s_b += y; s2_b += y * y;
  }
#pragma unroll
  for (int off = 32; off; off >>= 1) { s_b += __shfl_xor(s_b, off); s2_b += __shfl_xor(s2_b, off); }
  float mean2 = s_b * (1.f / 512.f);
  float inv2 = rsqrtf(s2_b * (1.f / 512.f) - mean2 * mean2 + 1e-5f);
#pragma unroll
  for (int j = 0; j < 8; j++) {
    int c = lane + j * 64;
    float y = (vals[j] - mean2) * inv2 * w2[c] + b2[c];
    xout[(size_t)row * 512 + c] = y;
    xbf[(size_t)row * 512 + c] = f2bf(y);
  }
}

// ---------------------------------------------------------------------------
// MFMA self-attention, one block per (batch, head). L=80, hd=64.
// ---------------------------------------------------------------------------
__global__ __launch_bounds__(256)
void attn_kernel(const unsigned short* __restrict__ qkv, unsigned short* __restrict__ o) {
  __shared__ __align__(16) unsigned short sq[80][72];
  __shared__ __align__(16) unsigned short sk[80][72];
  __shared__ __align__(16) unsigned short svT[64][96];
  __shared__ __align__(16) unsigned short sp[80][96];
  __shared__ float ss[80][84];
  const int tid = threadIdx.x;
  const int lane = tid & 63;
  const int wave = tid >> 6;
  const int bb = blockIdx.x >> 3, hh = blockIdx.x & 7;
  const unsigned short* base = qkv + (size_t)bb * 80 * 1536 + hh * 64;

  for (int idx = tid; idx < 5120; idx += 256) {
    int r = idx >> 6, c = idx & 63;
    sq[r][c] = base[r * 1536 + c];
    sk[r][c] = base[r * 1536 + 512 + c];
    svT[c][r] = base[r * 1536 + 1024 + c];
  }
  for (int idx = tid; idx < 1024; idx += 256) svT[idx >> 4][80 + (idx & 15)] = 0;
  for (int idx = tid; idx < 1280; idx += 256) sp[idx >> 4][80 + (idx & 15)] = 0;
  __syncthreads();

  const int fr = lane & 15;
  const int q = lane >> 4;

  // S = Q K^T (causal, *0.125)
  for (int t = wave; t < 25; t += 4) {
    int i0 = (t / 5) * 16, j0 = (t % 5) * 16;
    floatx4 acc = (floatx4){0.f, 0.f, 0.f, 0.f};
#pragma unroll
    for (int kk = 0; kk < 64; kk += 32) {
      short8 a = *(const short8*)&sq[i0 + fr][kk + q * 8];
      short8 b = *(const short8*)&sk[j0 + fr][kk + q * 8];
      acc = __builtin_amdgcn_mfma_f32_16x16x32_bf16(a, b, acc, 0, 0, 0);
    }
#pragma unroll
    for (int rg = 0; rg < 4; rg++) {
      int row = i0 + q * 4 + rg, col = j0 + fr;
      ss[row][col] = (col <= row) ? acc[rg] * 0.125f : -1e30f;
    }
  }
  __syncthreads();

  if (tid < 80) {
    float mx = -1e30f;
#pragma unroll
    for (int j = 0; j < 80; j++) mx = fmaxf(mx, ss[tid][j]);
    float sum = 0.f;
#pragma unroll
    for (int j = 0; j < 80; j++) { float e = __expf(ss[tid][j] - mx); ss[tid][j] = e; sum += e; }
    float inv = 1.f / sum;
#pragma unroll
    for (int j = 0; j < 80; j++) sp[tid][j] = f2bf(ss[tid][j] * inv);
  }
  __syncthreads();

  // O = P V  (K = 96, zero-padded)
  for (int t = wave; t < 20; t += 4) {
    int i0 = (t / 4) * 16, d0 = (t % 4) * 16;
    floatx4 acc = (floatx4){0.f, 0.f, 0.f, 0.f};
#pragma unroll
    for (int kk = 0; kk < 96; kk += 32) {
      short8 a = *(const short8*)&sp[i0 + fr][kk + q * 8];
      short8 b = *(const short8*)&svT[d0 + fr][kk + q * 8];
      acc = __builtin_amdgcn_mfma_f32_16x16x32_bf16(a, b, acc, 0, 0, 0);
    }
#pragma unroll
    for (int rg = 0; rg < 4; rg++) {
      int row = i0 + q * 4 + rg;
      o[((size_t)bb * 80 + row) * 512 + hh * 64 + d0 + fr] = f2bf(acc[rg]);
    }
  }
}

// ---------------------------------------------------------------------------
// Cross-attention constants for ALL layers: cav[l,e] = ca_out_b[l,e] +
// sum_f ca_out_w[l,e,f] * ca_in_b[l, 2E+f]   (mem==0, softmax over 1 key)
// ---------------------------------------------------------------------------
__global__ __launch_bounds__(256)
void cavec_kernel(const float* __restrict__ ca_out_w, const float* __restrict__ ca_in_b,
                  const float* __restrict__ ca_out_b, float* __restrict__ cav) {
  int g = blockIdx.x * 4 + (threadIdx.x >> 6);  // 0..2047 = layer*512 + e
  int lane = threadIdx.x & 63;
  int l = g >> 9, e = g & 511;
  const float* row = ca_out_w + ((size_t)l * 512 + e) * 512;
  const float* inb = ca_in_b + l * 1536 + 1024;
  float s = 0.f;
#pragma unroll
  for (int j = 0; j < 8; j++) s += row[lane + j * 64] * inb[lane + j * 64];
#pragma unroll
  for (int off = 32; off; off >>= 1) s += __shfl_xor(s, off);
  if (lane == 0) cav[g] = s + ca_out_b[l * 512 + e];
}

__global__ __launch_bounds__(256)
void convert_f2bf(const float* __restrict__ in, unsigned short* __restrict__ out, int n4) {
  int i = blockIdx.x * 256 + threadIdx.x;
  if (i < n4) {
    float4 v = ((const float4*)in)[i];
    ushort4 r;
    r.x = f2bf(v.x); r.y = f2bf(v.y); r.z = f2bf(v.z); r.w = f2bf(v.w);
    ((ushort4*)out)[i] = r;
  }
}

extern "C" void kernel_launch(void* const* d_in, const int* in_sizes, int n_in,
                              void* d_out, int out_size, void* d_ws, size_t ws_size,
                              hipStream_t stream) {
  const int*   caps     = (const int*)d_in[0];
  const float* W_in     = (const float*)d_in[1];
  const float* b_in     = (const float*)d_in[2];
  const float* pos_emb  = (const float*)d_in[3];
  const float* sa_in_w  = (const float*)d_in[4];
  const float* sa_in_b  = (const float*)d_in[5];
  const float* sa_out_w = (const float*)d_in[6];
  const float* sa_out_b = (const float*)d_in[7];
  const float* ca_in_b  = (const float*)d_in[9];
  const float* ca_out_w = (const float*)d_in[10];
  const float* ca_out_b = (const float*)d_in[11];
  const float* ff1_w    = (const float*)d_in[12];
  const float* ff1_b    = (const float*)d_in[13];
  const float* ff2_w    = (const float*)d_in[14];
  const float* ff2_b    = (const float*)d_in[15];
  const float* ln1_w    = (const float*)d_in[16];
  const float* ln1_b    = (const float*)d_in[17];
  const float* ln2_w    = (const float*)d_in[18];
  const float* ln2_b    = (const float*)d_in[19];
  const float* ln3_w    = (const float*)d_in[20];
  const float* ln3_b    = (const float*)d_in[21];
  const float* out_w    = (const float*)d_in[22];
  const float* out_b    = (const float*)d_in[23];

  char* ws = (char*)d_ws;
  size_t off = 0;
  auto alloc = [&](size_t bytes) {
    void* p = ws + off;
    off += (bytes + 255) & ~(size_t)255;
    return p;
  };
  unsigned short* w_sa_in  = (unsigned short*)alloc((size_t)4 * 1536 * 512 * 2);
  unsigned short* w_sa_out = (unsigned short*)alloc((size_t)4 * 512 * 512 * 2);
  unsigned short* w_ff1    = (unsigned short*)alloc((size_t)4 * 2048 * 512 * 2);
  unsigned short* w_ff2    = (unsigned short*)alloc((size_t)4 * 512 * 2048 * 2);
  unsigned short* w_out    = (unsigned short*)alloc((size_t)32000 * 512 * 2);
  float*          x        = (float*)alloc((size_t)2560 * 512 * 4);
  unsigned short* xbf      = (unsigned short*)alloc((size_t)2560 * 512 * 2);
  float*          t        = (float*)alloc((size_t)2560 * 512 * 4);
  unsigned short* qkv      = (unsigned short*)alloc((size_t)2560 * 1536 * 2);
  unsigned short* obf      = (unsigned short*)alloc((size_t)2560 * 512 * 2);
  unsigned short* hbf      = (unsigned short*)alloc((size_t)2560 * 2048 * 2);
  float*          cav      = (float*)alloc((size_t)2048 * 4);

  convert_f2bf<<<(786432 + 255) / 256, 256, 0, stream>>>(sa_in_w, w_sa_in, 786432);
  convert_f2bf<<<(262144 + 255) / 256, 256, 0, stream>>>(sa_out_w, w_sa_out, 262144);
  convert_f2bf<<<(1048576 + 255) / 256, 256, 0, stream>>>(ff1_w, w_ff1, 1048576);
  convert_f2bf<<<(1048576 + 255) / 256, 256, 0, stream>>>(ff2_w, w_ff2, 1048576);
  convert_f2bf<<<(4096000 + 255) / 256, 256, 0, stream>>>(out_w, w_out, 4096000);

  embed_kernel<<<2560, 512, 0, stream>>>(caps, W_in, b_in, pos_emb, x, xbf);
  cavec_kernel<<<512, 256, 0, stream>>>(ca_out_w, ca_in_b, ca_out_b, cav);

  for (int i = 0; i < 4; i++) {
    gemm_bt<128, 64, 1, 0><<<dim3(20, 24), 256, 0, stream>>>(
        xbf, w_sa_in + (size_t)i * 1536 * 512, sa_in_b + i * 1536, nullptr,
        qkv, 2560, 1536, 512);
    attn_kernel<<<256, 256, 0, stream>>>(qkv, obf);
    gemm_bt<64, 64, 0, 0><<<dim3(40, 8), 256, 0, stream>>>(
        obf, w_sa_out + (size_t)i * 512 * 512, sa_out_b + i * 512, x,
        t, 2560, 512, 512);
    ln2x_kernel<<<640, 256, 0, stream>>>(t, cav + i * 512,
        ln1_w + i * 512, ln1_b + i * 512, ln2_w + i * 512, ln2_b + i * 512, x, xbf);
    gemm_bt<128, 64, 1, 1><<<dim3(20, 32), 256, 0, stream>>>(
        xbf, w_ff1 + (size_t)i * 2048 * 512, ff1_b + i * 2048, nullptr,
        hbf, 2560, 2048, 512);
    gemm_bt<64, 64, 0, 0><<<dim3(40, 8), 256, 0, stream>>>(
        hbf, w_ff2 + (size_t)i * 512 * 2048, ff2_b + i * 512, x,
        t, 2560, 512, 2048);
    ln_kernel<<<640, 256, 0, stream>>>(t, ln3_w + i * 512, ln3_b + i * 512, x, xbf);
  }

  gemm_vocab<<<250, 512, 0, stream>>>(xbf, w_out, out_b, (float*)d_out, 2560, 32000);
}

// Round 6
// 1070.151 us; speedup vs baseline: 1.0701x; 1.0701x over previous
//
#include <hip/hip_runtime.h>

typedef __attribute__((ext_vector_type(8))) short short8;
typedef __attribute__((ext_vector_type(4))) float floatx4;

__device__ __forceinline__ unsigned short f2bf(float f) {
  union { float f; unsigned int u; } un; un.f = f;
  unsigned int r = un.u + 0x7FFFu + ((un.u >> 16) & 1u);
  return (unsigned short)(r >> 16);
}

__device__ __forceinline__ void async_ld16(const unsigned short* g, unsigned short* l) {
  __builtin_amdgcn_global_load_lds(
      (const __attribute__((address_space(1))) void*)g,
      (__attribute__((address_space(3))) void*)l, 16, 0, 0);
}

// ---------------------------------------------------------------------------
// Persistent vocab GEMM: C[M,32000] = A[M,512](bf16) @ W[32000,512](fp32)^T + b.
// Round-3 schedule (best measured: 263 µs). B slab read ONCE per block from
// the FP32 weights directly (coalesced float4 -> f2bf -> swizzled ds_write)
// — deletes the separate 192-MB out_w convert dispatch.
// LDS = 128 KB (B slab, XOR-swz) + 2x8 KB (A dbuf) = 144 KB -> 1 block/CU,
// 512 thr (8 waves 2Mx4N). Grid = 250 = N/128, block persistent over all M.
// ---------------------------------------------------------------------------
__global__ __launch_bounds__(512, 1)
void gemm_vocab(const unsigned short* __restrict__ A, const float* __restrict__ Bf,
                const float* __restrict__ bias, float* __restrict__ C, int M, int N) {
  __shared__ __align__(16) unsigned short sB[65536];    // [128][512] elems, XOR-swz
  __shared__ __align__(16) unsigned short sA[2][4096];  // [64][64] per buf, XOR-swz
  const int tid = threadIdx.x;
  const int lane = tid & 63;
  const int wave = tid >> 6;
  const int n0 = blockIdx.x * 128;
  const int fr = lane & 15;
  const int q = lane >> 4;
  const int wm = (wave >> 2) * 32;  // 2 wave-rows over 64
  const int wn = (wave & 3) * 32;   // 4 wave-cols over 128

  // ---- prologue: stage full B n-slab from FP32 weights (reg-staged).
  // Writer puts data col-block `lane` at slot lane^(rr&7); reader at slot
  // cbi^(rb&7) therefore recovers col-block cbi (same involution).
  for (int ro = 0; ro < 16; ro++) {
    int rr = ro * 8 + wave;
    const float* src = Bf + (size_t)(n0 + rr) * 512 + lane * 8;
    float4 v0 = ((const float4*)src)[0];
    float4 v1 = ((const float4*)src)[1];
    short8 w;
    w[0] = (short)f2bf(v0.x); w[1] = (short)f2bf(v0.y);
    w[2] = (short)f2bf(v0.z); w[3] = (short)f2bf(v0.w);
    w[4] = (short)f2bf(v1.x); w[5] = (short)f2bf(v1.y);
    w[6] = (short)f2bf(v1.z); w[7] = (short)f2bf(v1.w);
    *(short8*)&sB[rr * 512 + ((lane ^ (rr & 7)) << 3)] = w;
  }

  // A stage for flat step s (mt = s>>3, kt = s&7): 64x64 tile, 1 ld/thread.
  auto stage_a = [&](int s, int buf) {
    int mt = s >> 3, kt = s & 7;
    int r = tid >> 3, cb = tid & 7;
    async_ld16(A + (size_t)(mt * 64 + r) * 512 + (kt << 6) + ((cb ^ (r & 7)) << 3),
               &sA[buf][wave * 512]);
  };

  floatx4 acc[2][2];
#pragma unroll
  for (int i = 0; i < 2; i++)
#pragma unroll
    for (int j = 0; j < 2; j++) acc[i][j] = (floatx4){0.f, 0.f, 0.f, 0.f};

  stage_a(0, 0);
  const int nsteps = (M >> 6) << 3;
  for (int s = 0; s < nsteps; s++) {
    __syncthreads();  // drains prologue ds_writes (s=0) / stage(s) + reads
    if (s + 1 < nsteps) stage_a(s + 1, (s + 1) & 1);
    const unsigned short* pA = sA[s & 1];
    const int kt = s & 7;
#pragma unroll
    for (int kk = 0; kk < 64; kk += 32) {
      const int cba = (kk >> 3) + q;
      short8 af[2], bfr[2];
#pragma unroll
      for (int t = 0; t < 2; t++) {
        int ra = wm + t * 16 + fr;
        af[t] = *(const short8*)&pA[ra * 64 + ((cba ^ (ra & 7)) << 3)];
        int rb = wn + t * 16 + fr;
        int cbi = (kt << 3) + cba;
        bfr[t] = *(const short8*)&sB[rb * 512 + ((cbi ^ (rb & 7)) << 3)];
      }
#pragma unroll
      for (int i = 0; i < 2; i++)
#pragma unroll
        for (int j = 0; j < 2; j++)
          acc[i][j] = __builtin_amdgcn_mfma_f32_16x16x32_bf16(af[i], bfr[j], acc[i][j], 0, 0, 0);
    }
    if (kt == 7) {
      const int mt = s >> 3;
#pragma unroll
      for (int i = 0; i < 2; i++)
#pragma unroll
        for (int j = 0; j < 2; j++) {
#pragma unroll
          for (int rg = 0; rg < 4; rg++) {
            int row = mt * 64 + wm + i * 16 + q * 4 + rg;
            int col = n0 + wn + j * 16 + fr;
            C[(size_t)row * N + col] = acc[i][j][rg] + bias[col];
          }
          acc[i][j] = (floatx4){0.f, 0.f, 0.f, 0.f};
        }
    }
  }
}

// ---------------------------------------------------------------------------
// GEMM: C[M,N] = A[M,K](bf16 rm) @ W[N,K](bf16 rm)^T + bias (+res fp32, relu).
// TM in {128,64,32}, TN=64. BK=64, 256 thr (4 waves 2x2), mfma 16x16x32.
// Triple-buffered LDS, counted vmcnt, raw barriers. T1 XCD-chunked remap.
// ROUND-5 BUG FIX: lb[] (LDS staging offsets) was initialized only for AIT
// entries; with TM=32 (AIT=1 < BIT=2) the B-stage used lb[1] UNINITIALIZED
// -> garbage LDS dest -> NaN. Now initialized for max(AIT,BIT).
// ---------------------------------------------------------------------------
template<int TM, int TN, int OUT_BF16, int RELU>
__global__ __launch_bounds__(256, (TM == 32) ? 4 : (TM == 64) ? 3 : 2)
void gemm_bt(const unsigned short* __restrict__ A, const unsigned short* __restrict__ B,
             const float* __restrict__ bias, const float* __restrict__ res,
             void* __restrict__ Cout, int M, int N, int K) {
  constexpr int AELEM = TM * 64;
  constexpr int BELEM = TN * 64;
  constexpr int AIT = AELEM / 2048;
  constexpr int BIT = BELEM / 2048;
  constexpr int LPS = AIT + BIT;   // global_load_lds per thread per stage
  constexpr int LBN = (AIT > BIT) ? AIT : BIT;
  constexpr int FM = (TM + 31) / 32;
  constexpr int FN = TN / 32;
  __shared__ __align__(16) unsigned short sA[3][AELEM];
  __shared__ __align__(16) unsigned short sB[3][BELEM];
  const int tid = threadIdx.x;
  const int lane = tid & 63;
  const int wave = tid >> 6;

  // T1: bijective XCD-chunked remap (hardware round-robins linear id % 8).
  const int gx = gridDim.x;
  const int nwg = gx * gridDim.y;
  const int ord = blockIdx.y * gx + blockIdx.x;
  const int qq = nwg >> 3, rr = nwg & 7;
  const int xcd = ord & 7, idx = ord >> 3;
  const int lin = (xcd < rr) ? (xcd * (qq + 1) + idx)
                             : (rr * (qq + 1) + (xcd - rr) * qq + idx);
  const int m0 = (lin % gx) * TM;   // M fast within an XCD chunk -> B-slab reuse
  const int n0 = (lin / gx) * TN;

  int a_off[AIT], b_off[BIT], lb[LBN];
#pragma unroll
  for (int it = 0; it < LBN; it++) lb[it] = it * 2048 + wave * 512;
#pragma unroll
  for (int it = 0; it < AIT; it++) {
    int e = it * 2048 + tid * 8;
    int r = e >> 6, cb = (e >> 3) & 7;
    a_off[it] = (m0 + r) * K + ((cb ^ (r & 7)) * 8);
  }
#pragma unroll
  for (int it = 0; it < BIT; it++) {
    int e = it * 2048 + tid * 8;
    int r = e >> 6, cb = (e >> 3) & 7;
    b_off[it] = (n0 + r) * K + ((cb ^ (r & 7)) * 8);
  }

  floatx4 acc[FM][FN];
#pragma unroll
  for (int i = 0; i < FM; i++)
#pragma unroll
    for (int j = 0; j < FN; j++) acc[i][j] = (floatx4){0.f, 0.f, 0.f, 0.f};

  const int nkt = K >> 6;
  const int wm = (wave >> 1) * (TM / 2);
  const int wn = (wave & 1) * (TN / 2);
  const int fr = lane & 15;
  const int q = lane >> 4;

  auto stage = [&](int kt, int buf) {
    const int k0 = kt << 6;
#pragma unroll
    for (int it = 0; it < AIT; it++) async_ld16(A + (size_t)a_off[it] + k0, &sA[buf][lb[it]]);
#pragma unroll
    for (int it = 0; it < BIT; it++) async_ld16(B + (size_t)b_off[it] + k0, &sB[buf][lb[it]]);
  };

  stage(0, 0);
  if (nkt > 1) stage(1, 1);
  if (nkt > 2) stage(2, 2);

  int buf = 0;
  for (int kt = 0; kt < nkt; kt++) {
    const int rem = nkt - 1 - kt;  // stages still in flight beyond kt after our wait
    if (rem >= 2)      asm volatile("s_waitcnt vmcnt(%0)" :: "n"(2 * LPS) : "memory");
    else if (rem == 1) asm volatile("s_waitcnt vmcnt(%0)" :: "n"(LPS) : "memory");
    else               asm volatile("s_waitcnt vmcnt(0)" ::: "memory");
    __builtin_amdgcn_s_barrier();   // buf[kt%3] fully staged for every wave

    const unsigned short* pA = sA[buf];
    const unsigned short* pB = sB[buf];
#pragma unroll
    for (int kk = 0; kk < 64; kk += 32) {
      short8 af[FM], bfr[FN];
      const int cba = (kk >> 3) + q;
#pragma unroll
      for (int t = 0; t < FM; t++) {
        int ra = wm + t * 16 + fr;
        af[t] = *(const short8*)&pA[ra * 64 + ((cba ^ (ra & 7)) * 8)];
      }
#pragma unroll
      for (int t = 0; t < FN; t++) {
        int rb = wn + t * 16 + fr;
        bfr[t] = *(const short8*)&pB[rb * 64 + ((cba ^ (rb & 7)) * 8)];
      }
#pragma unroll
      for (int i = 0; i < FM; i++)
#pragma unroll
        for (int j = 0; j < FN; j++)
          acc[i][j] = __builtin_amdgcn_mfma_f32_16x16x32_bf16(af[i], bfr[j], acc[i][j], 0, 0, 0);
    }

    asm volatile("s_waitcnt lgkmcnt(0)" ::: "memory");  // my reads of buf done
    __builtin_amdgcn_s_barrier();                        // everyone's reads done
    if (kt + 3 < nkt) stage(kt + 3, buf);                // overwrite is now safe
    buf = (buf == 2) ? 0 : buf + 1;
  }

#pragma unroll
  for (int i = 0; i < FM; i++) {
#pragma unroll
    for (int j = 0; j < FN; j++) {
#pragma unroll
      for (int rg = 0; rg < 4; rg++) {
        int row = m0 + wm + i * 16 + q * 4 + rg;
        int col = n0 + wn + j * 16 + fr;
        float v = acc[i][j][rg];
        if (bias) v += bias[col];
        if (res)  v += res[(size_t)row * N + col];
        if (RELU) v = v > 0.f ? v : 0.f;
        if (OUT_BF16) ((unsigned short*)Cout)[(size_t)row * N + col] = f2bf(v);
        else          ((float*)Cout)[(size_t)row * N + col] = v;
      }
    }
  }
}

// ---------------------------------------------------------------------------
// Merged embed + cavec (one dispatch instead of two).
// blocks [0,2560): x[p,e] = W_in[e, caps[p]] + b_in[e] + pos_emb[p%80, e]
// blocks [2560,2816): cav[l,e] = ca_out_b[l,e] + ca_out_w[l,e,:] . ca_in_b[l,2E:]
// ---------------------------------------------------------------------------
__global__ __launch_bounds__(512)
void embed_cavec_kernel(const int* __restrict__ caps, const float* __restrict__ W_in,
                        const float* __restrict__ b_in, const float* __restrict__ pos,
                        float* __restrict__ x, unsigned short* __restrict__ xbf,
                        const float* __restrict__ ca_out_w, const float* __restrict__ ca_in_b,
                        const float* __restrict__ ca_out_b, float* __restrict__ cav) {
  int bid = blockIdx.x;
  if (bid < 2560) {
    int l = bid % 80;
    int tok = caps[bid];
    int e = threadIdx.x;
    float v = W_in[(size_t)e * 32000 + tok] + b_in[e] + pos[l * 512 + e];
    x[(size_t)bid * 512 + e] = v;
    xbf[(size_t)bid * 512 + e] = f2bf(v);
  } else {
    int wave = threadIdx.x >> 6, lane = threadIdx.x & 63;
    int g = (bid - 2560) * 8 + wave;  // 0..2047 = layer*512 + e
    int l = g >> 9, e = g & 511;
    const float* row = ca_out_w + ((size_t)l * 512 + e) * 512;
    const float* inb = ca_in_b + l * 1536 + 1024;
    float s = 0.f;
#pragma unroll
    for (int j = 0; j < 8; j++) s += row[lane + j * 64] * inb[lane + j * 64];
#pragma unroll
    for (int off = 32; off; off >>= 1) s += __shfl_xor(s, off);
    if (lane == 0) cav[g] = s + ca_out_b[l * 512 + e];
  }
}

// ---------------------------------------------------------------------------
// Single LayerNorm (for LN3). One wave per row (E=512, 8 vals/lane).
// ---------------------------------------------------------------------------
__global__ __launch_bounds__(256)
void ln_kernel(const float* __restrict__ in, const float* __restrict__ w,
               const float* __restrict__ b, float* __restrict__ xout,
               unsigned short* __restrict__ xbf) {
  int row = blockIdx.x * 4 + (threadIdx.x >> 6);
  int lane = threadIdx.x & 63;
  const float* p = in + (size_t)row * 512;
  float vals[8];
  float s = 0.f, s2 = 0.f;
#pragma unroll
  for (int j = 0; j < 8; j++) {
    float t = p[lane + j * 64];
    vals[j] = t; s += t; s2 += t * t;
  }
#pragma unroll
  for (int off = 32; off; off >>= 1) { s += __shfl_xor(s, off); s2 += __shfl_xor(s2, off); }
  float mean = s * (1.f / 512.f);
  float inv = rsqrtf(s2 * (1.f / 512.f) - mean * mean + 1e-5f);
#pragma unroll
  for (int j = 0; j < 8; j++) {
    int c = lane + j * 64;
    float y = (vals[j] - mean) * inv * w[c] + b[c];
    xout[(size_t)row * 512 + c] = y;
    xbf[(size_t)row * 512 + c] = f2bf(y);
  }
}

// ---------------------------------------------------------------------------
// Fused LN1 -> +cav -> LN2 (saves a kernel + a full x round-trip per layer).
// ---------------------------------------------------------------------------
__global__ __launch_bounds__(256)
void ln2x_kernel(const float* __restrict__ in, const float* __restrict__ cav,
                 const float* __restrict__ w1, const float* __restrict__ b1,
                 const float* __restrict__ w2, const float* __restrict__ b2,
                 float* __restrict__ xout, unsigned short* __restrict__ xbf) {
  int row = blockIdx.x * 4 + (threadIdx.x >> 6);
  int lane = threadIdx.x & 63;
  const float* p = in + (size_t)row * 512;
  float vals[8];
  float s = 0.f, s2 = 0.f;
#pragma unroll
  for (int j = 0; j < 8; j++) {
    float t = p[lane + j * 64];
    vals[j] = t; s += t; s2 += t * t;
  }
#pragma unroll
  for (int off = 32; off; off >>= 1) { s += __shfl_xor(s, off); s2 += __shfl_xor(s2, off); }
  float mean = s * (1.f / 512.f);
  float inv = rsqrtf(s2 * (1.f / 512.f) - mean * mean + 1e-5f);
  float s_b = 0.f, s2_b = 0.f;
#pragma unroll
  for (int j = 0; j < 8; j++) {
    int c = lane + j * 64;
    float y = (vals[j] - mean) * inv * w1[c] + b1[c] + cav[c];
    vals[j] = y; s_b += y; s2_b += y * y;
  }
#pragma unroll
  for (int off = 32; off; off >>= 1) { s_b += __shfl_xor(s_b, off); s2_b += __shfl_xor(s2_b, off); }
  float mean2 = s_b * (1.f / 512.f);
  float inv2 = rsqrtf(s2_b * (1.f / 512.f) - mean2 * mean2 + 1e-5f);
#pragma unroll
  for (int j = 0; j < 8; j++) {
    int c = lane + j * 64;
    float y = (vals[j] - mean2) * inv2 * w2[c] + b2[c];
    xout[(size_t)row * 512 + c] = y;
    xbf[(size_t)row * 512 + c] = f2bf(y);
  }
}

// ---------------------------------------------------------------------------
// MFMA self-attention, one block per (batch, head). L=80, hd=64.
// ---------------------------------------------------------------------------
__global__ __launch_bounds__(256)
void attn_kernel(const unsigned short* __restrict__ qkv, unsigned short* __restrict__ o) {
  __shared__ __align__(16) unsigned short sq[80][72];
  __shared__ __align__(16) unsigned short sk[80][72];
  __shared__ __align__(16) unsigned short svT[64][96];
  __shared__ __align__(16) unsigned short sp[80][96];
  __shared__ float ss[80][84];
  const int tid = threadIdx.x;
  const int lane = tid & 63;
  const int wave = tid >> 6;
  const int bb = blockIdx.x >> 3, hh = blockIdx.x & 7;
  const unsigned short* base = qkv + (size_t)bb * 80 * 1536 + hh * 64;

  for (int idx = tid; idx < 5120; idx += 256) {
    int r = idx >> 6, c = idx & 63;
    sq[r][c] = base[r * 1536 + c];
    sk[r][c] = base[r * 1536 + 512 + c];
    svT[c][r] = base[r * 1536 + 1024 + c];
  }
  for (int idx = tid; idx < 1024; idx += 256) svT[idx >> 4][80 + (idx & 15)] = 0;
  for (int idx = tid; idx < 1280; idx += 256) sp[idx >> 4][80 + (idx & 15)] = 0;
  __syncthreads();

  const int fr = lane & 15;
  const int q = lane >> 4;

  // S = Q K^T (causal, *0.125)
  for (int t = wave; t < 25; t += 4) {
    int i0 = (t / 5) * 16, j0 = (t % 5) * 16;
    floatx4 acc = (floatx4){0.f, 0.f, 0.f, 0.f};
#pragma unroll
    for (int kk = 0; kk < 64; kk += 32) {
      short8 a = *(const short8*)&sq[i0 + fr][kk + q * 8];
      short8 b = *(const short8*)&sk[j0 + fr][kk + q * 8];
      acc = __builtin_amdgcn_mfma_f32_16x16x32_bf16(a, b, acc, 0, 0, 0);
    }
#pragma unroll
    for (int rg = 0; rg < 4; rg++) {
      int row = i0 + q * 4 + rg, col = j0 + fr;
      ss[row][col] = (col <= row) ? acc[rg] * 0.125f : -1e30f;
    }
  }
  __syncthreads();

  if (tid < 80) {
    float mx = -1e30f;
#pragma unroll
    for (int j = 0; j < 80; j++) mx = fmaxf(mx, ss[tid][j]);
    float sum = 0.f;
#pragma unroll
    for (int j = 0; j < 80; j++) { float e = __expf(ss[tid][j] - mx); ss[tid][j] = e; sum += e; }
    float inv = 1.f / sum;
#pragma unroll
    for (int j = 0; j < 80; j++) sp[tid][j] = f2bf(ss[tid][j] * inv);
  }
  __syncthreads();

  // O = P V  (K = 96, zero-padded)
  for (int t = wave; t < 20; t += 4) {
    int i0 = (t / 4) * 16, d0 = (t % 4) * 16;
    floatx4 acc = (floatx4){0.f, 0.f, 0.f, 0.f};
#pragma unroll
    for (int kk = 0; kk < 96; kk += 32) {
      short8 a = *(const short8*)&sp[i0 + fr][kk + q * 8];
      short8 b = *(const short8*)&svT[d0 + fr][kk + q * 8];
      acc = __builtin_amdgcn_mfma_f32_16x16x32_bf16(a, b, acc, 0, 0, 0);
    }
#pragma unroll
    for (int rg = 0; rg < 4; rg++) {
      int row = i0 + q * 4 + rg;
      o[((size_t)bb * 80 + row) * 512 + hh * 64 + d0 + fr] = f2bf(acc[rg]);
    }
  }
}

// ---------------------------------------------------------------------------
// One merged bf16 conversion for the 4 layer-weight tensors (1 dispatch).
// Sizes in float4 units: sa_in 786432, sa_out 262144, ff1 1048576, ff2 1048576.
// ---------------------------------------------------------------------------
__global__ __launch_bounds__(256)
void convert_all(const float* __restrict__ s0, unsigned short* __restrict__ d0,
                 const float* __restrict__ s1, unsigned short* __restrict__ d1,
                 const float* __restrict__ s2, unsigned short* __restrict__ d2,
                 const float* __restrict__ s3, unsigned short* __restrict__ d3) {
  int i = blockIdx.x * 256 + threadIdx.x;
  const float* s; unsigned short* d; int j = i;
  if (j < 786432) { s = s0; d = d0; }
  else if ((j -= 786432) < 262144) { s = s1; d = d1; }
  else if ((j -= 262144) < 1048576) { s = s2; d = d2; }
  else { j -= 1048576; s = s3; d = d3; }
  float4 v = ((const float4*)s)[j];
  ushort4 r;
  r.x = f2bf(v.x); r.y = f2bf(v.y); r.z = f2bf(v.z); r.w = f2bf(v.w);
  ((ushort4*)d)[j] = r;
}

extern "C" void kernel_launch(void* const* d_in, const int* in_sizes, int n_in,
                              void* d_out, int out_size, void* d_ws, size_t ws_size,
                              hipStream_t stream) {
  const int*   caps     = (const int*)d_in[0];
  const float* W_in     = (const float*)d_in[1];
  const float* b_in     = (const float*)d_in[2];
  const float* pos_emb  = (const float*)d_in[3];
  const float* sa_in_w  = (const float*)d_in[4];
  const float* sa_in_b  = (const float*)d_in[5];
  const float* sa_out_w = (const float*)d_in[6];
  const float* sa_out_b = (const float*)d_in[7];
  const float* ca_in_b  = (const float*)d_in[9];
  const float* ca_out_w = (const float*)d_in[10];
  const float* ca_out_b = (const float*)d_in[11];
  const float* ff1_w    = (const float*)d_in[12];
  const float* ff1_b    = (const float*)d_in[13];
  const float* ff2_w    = (const float*)d_in[14];
  const float* ff2_b    = (const float*)d_in[15];
  const float* ln1_w    = (const float*)d_in[16];
  const float* ln1_b    = (const float*)d_in[17];
  const float* ln2_w    = (const float*)d_in[18];
  const float* ln2_b    = (const float*)d_in[19];
  const float* ln3_w    = (const float*)d_in[20];
  const float* ln3_b    = (const float*)d_in[21];
  const float* out_w    = (const float*)d_in[22];
  const float* out_b    = (const float*)d_in[23];

  char* ws = (char*)d_ws;
  size_t off = 0;
  auto alloc = [&](size_t bytes) {
    void* p = ws + off;
    off += (bytes + 255) & ~(size_t)255;
    return p;
  };
  unsigned short* w_sa_in  = (unsigned short*)alloc((size_t)4 * 1536 * 512 * 2);
  unsigned short* w_sa_out = (unsigned short*)alloc((size_t)4 * 512 * 512 * 2);
  unsigned short* w_ff1    = (unsigned short*)alloc((size_t)4 * 2048 * 512 * 2);
  unsigned short* w_ff2    = (unsigned short*)alloc((size_t)4 * 512 * 2048 * 2);
  float*          x        = (float*)alloc((size_t)2560 * 512 * 4);
  unsigned short* xbf      = (unsigned short*)alloc((size_t)2560 * 512 * 2);
  float*          t        = (float*)alloc((size_t)2560 * 512 * 4);
  unsigned short* qkv      = (unsigned short*)alloc((size_t)2560 * 1536 * 2);
  unsigned short* obf      = (unsigned short*)alloc((size_t)2560 * 512 * 2);
  unsigned short* hbf      = (unsigned short*)alloc((size_t)2560 * 2048 * 2);
  float*          cav      = (float*)alloc((size_t)2048 * 4);

  // one dispatch for all four layer-weight conversions (out_w stays fp32;
  // the vocab kernel converts it in-LDS during its one-time B prologue)
  convert_all<<<12288, 256, 0, stream>>>(sa_in_w, w_sa_in, sa_out_w, w_sa_out,
                                         ff1_w, w_ff1, ff2_w, w_ff2);
  embed_cavec_kernel<<<2816, 512, 0, stream>>>(caps, W_in, b_in, pos_emb, x, xbf,
                                               ca_out_w, ca_in_b, ca_out_b, cav);

  for (int i = 0; i < 4; i++) {
    gemm_bt<128, 64, 1, 0><<<dim3(20, 24), 256, 0, stream>>>(
        xbf, w_sa_in + (size_t)i * 1536 * 512, sa_in_b + i * 1536, nullptr,
        qkv, 2560, 1536, 512);
    attn_kernel<<<256, 256, 0, stream>>>(qkv, obf);
    gemm_bt<32, 64, 0, 0><<<dim3(80, 8), 256, 0, stream>>>(
        obf, w_sa_out + (size_t)i * 512 * 512, sa_out_b + i * 512, x,
        t, 2560, 512, 512);
    ln2x_kernel<<<640, 256, 0, stream>>>(t, cav + i * 512,
        ln1_w + i * 512, ln1_b + i * 512, ln2_w + i * 512, ln2_b + i * 512, x, xbf);
    gemm_bt<128, 64, 1, 1><<<dim3(20, 32), 256, 0, stream>>>(
        xbf, w_ff1 + (size_t)i * 2048 * 512, ff1_b + i * 2048, nullptr,
        hbf, 2560, 2048, 512);
    gemm_bt<32, 64, 0, 0><<<dim3(80, 8), 256, 0, stream>>>(
        hbf, w_ff2 + (size_t)i * 512 * 2048, ff2_b + i * 512, x,
        t, 2560, 512, 2048);
    ln_kernel<<<640, 256, 0, stream>>>(t, ln3_w + i * 512, ln3_b + i * 512, x, xbf);
  }

  gemm_vocab<<<250, 512, 0, stream>>>(xbf, out_w, out_b, (float*)d_out, 2560, 32000);
}